// Round 4
// baseline (460.934 us; speedup 1.0000x reference)
//
#include <hip/hip_runtime.h>

#define N_NODES 100000
#define N_EDGES 600000
#define N_GRAPHS 64

// ---------------- CSR build ----------------

__global__ void k_count(const int* __restrict__ dst, int* __restrict__ deg) {
    int e = blockIdx.x * 256 + threadIdx.x;
    if (e < N_EDGES) atomicAdd(&deg[dst[e]], 1);
}

__global__ void k_scan1(const int* __restrict__ deg, int* __restrict__ offs,
                        int* __restrict__ bsums) {
    __shared__ int s[256];
    int t = threadIdx.x, b = blockIdx.x;
    int base = b * 1024 + t * 4;
    int v0 = (base + 0 < N_NODES) ? deg[base + 0] : 0;
    int v1 = (base + 1 < N_NODES) ? deg[base + 1] : 0;
    int v2 = (base + 2 < N_NODES) ? deg[base + 2] : 0;
    int v3 = (base + 3 < N_NODES) ? deg[base + 3] : 0;
    int tsum = v0 + v1 + v2 + v3;
    s[t] = tsum;
    __syncthreads();
    for (int o = 1; o < 256; o <<= 1) {
        int x = (t >= o) ? s[t - o] : 0;
        __syncthreads();
        s[t] += x;
        __syncthreads();
    }
    int p = s[t] - tsum;
    if (base + 0 < N_NODES) offs[base + 0] = p;
    p += v0;
    if (base + 1 < N_NODES) offs[base + 1] = p;
    p += v1;
    if (base + 2 < N_NODES) offs[base + 2] = p;
    p += v2;
    if (base + 3 < N_NODES) offs[base + 3] = p;
    if (t == 255) bsums[b] = s[255];
}

__global__ void k_scan2(const int* __restrict__ bsums, int* __restrict__ boff) {
    __shared__ int s[128];
    int t = threadIdx.x;
    int nb = (N_NODES + 1023) / 1024;
    int v = (t < nb) ? bsums[t] : 0;
    s[t] = v;
    __syncthreads();
    for (int o = 1; o < 128; o <<= 1) {
        int x = (t >= o) ? s[t - o] : 0;
        __syncthreads();
        s[t] += x;
        __syncthreads();
    }
    boff[t] = s[t] - v;
}

__global__ void k_scan3(int* __restrict__ offs, const int* __restrict__ boff,
                        int* __restrict__ cursor) {
    int i = blockIdx.x * 256 + threadIdx.x;
    if (i < N_NODES) {
        int v = offs[i] + boff[i >> 10];
        offs[i] = v;
        cursor[i] = v;
    }
}

__global__ void k_fill(const int* __restrict__ src, const int* __restrict__ dst,
                       int* __restrict__ cursor, int* __restrict__ ssrc) {
    int e = blockIdx.x * 256 + threadIdx.x;
    if (e < N_EDGES) {
        int d = dst[e];
        int pos = atomicAdd(&cursor[d], 1);
        ssrc[pos] = src[e];
    }
}

// Wsc1[m][d] (m<64: (W1l[d][2m],W1l[d][2m+1]); m>=64: W1r pairs) — scalar-load layout
__global__ void k_prepack1(const float* __restrict__ W1l, const float* __restrict__ W1r,
                           float2* __restrict__ Wsc) {
    int i = blockIdx.x * 256 + threadIdx.x;
    if (i < 128 * 64) {
        int m = i >> 6, d = i & 63;
        Wsc[i] = (m < 64) ? make_float2(W1l[d * 128 + 2 * m], W1l[d * 128 + 2 * m + 1])
                          : make_float2(W1r[d * 128 + 2 * (m - 64)], W1r[d * 128 + 2 * (m - 64) + 1]);
    }
}

__global__ void k_prepack2(const float* __restrict__ W2l, const float* __restrict__ W2r,
                           float2* __restrict__ Wsc) {
    int i = blockIdx.x * 256 + threadIdx.x;
    if (i < 64 * 16) {
        int m = i >> 4, d = i & 15;
        Wsc[i] = (m < 32) ? make_float2(W2l[d * 64 + 2 * m], W2l[d * 64 + 2 * m + 1])
                          : make_float2(W2r[d * 64 + 2 * (m - 32)], W2r[d * 64 + 2 * (m - 32) + 1]);
    }
}

// ---------------- SAGE layer 1: gather->swizzled LDS, then lane=node transform ----
// LDS float2 tile: node n, element m in [0,128) at S[n*128 + (m ^ (n&15))]
// m<64: (mean[2m],mean[2m+1]) ; m>=64: (x[2m'],x[2m'+1])

__launch_bounds__(256)
__global__ void k_layer1(const float* __restrict__ x, const int* __restrict__ ssrc,
                         const int* __restrict__ offs, const int* __restrict__ deg,
                         const float2* __restrict__ Wsc, const float* __restrict__ b1,
                         float* __restrict__ h1) {
    __shared__ float2 S[64 * 128];  // 64 KB
    int tid = threadIdx.x;
    int wave = __builtin_amdgcn_readfirstlane(tid >> 6);
    int lane = tid & 63;
    const float2* x2 = (const float2*)x;

    int nTiles = (N_NODES + 63) / 64;
    for (int tile = blockIdx.x; tile < nTiles; tile += gridDim.x) {
        int tbase = tile * 64;
        // phase A: each wave gathers 16 nodes (lane = k-pair)
        for (int j = wave * 16; j < wave * 16 + 16; ++j) {
            int node = tbase + j;
            if (node < N_NODES) {
                int o  = __builtin_amdgcn_readfirstlane(offs[node]);
                int dg = __builtin_amdgcn_readfirstlane(deg[node]);
                float ax0 = 0.f, ay0 = 0.f, ax1 = 0.f, ay1 = 0.f;
                float ax2 = 0.f, ay2 = 0.f, ax3 = 0.f, ay3 = 0.f;
                int last = dg - 1;
                for (int u = 0; u < dg; u += 4) {
                    int n0 = ssrc[o + u];
                    int n1 = ssrc[o + min(u + 1, last)];
                    int n2 = ssrc[o + min(u + 2, last)];
                    int n3 = ssrc[o + min(u + 3, last)];
                    float2 v0 = x2[n0 * 64 + lane];
                    float2 v1 = x2[n1 * 64 + lane];
                    float2 v2 = x2[n2 * 64 + lane];
                    float2 v3 = x2[n3 * 64 + lane];
                    float m1 = (u + 1 < dg) ? 1.f : 0.f;
                    float m2 = (u + 2 < dg) ? 1.f : 0.f;
                    float m3 = (u + 3 < dg) ? 1.f : 0.f;
                    ax0 += v0.x;               ay0 += v0.y;
                    ax1 = fmaf(v1.x, m1, ax1); ay1 = fmaf(v1.y, m1, ay1);
                    ax2 = fmaf(v2.x, m2, ax2); ay2 = fmaf(v2.y, m2, ay2);
                    ax3 = fmaf(v3.x, m3, ax3); ay3 = fmaf(v3.y, m3, ay3);
                }
                float inv = 1.f / (float)max(dg, 1);
                float2 xi = x2[node * 64 + lane];
                int sw = lane ^ (j & 15);
                S[j * 128 + sw]      = make_float2(((ax0 + ax1) + (ax2 + ax3)) * inv,
                                                   ((ay0 + ay1) + (ay2 + ay3)) * inv);
                S[j * 128 + 64 + sw] = make_float2(xi.x, xi.y);
            }
        }
        __syncthreads();
        // phase B: lane = node, wave owns 16 output dims; W via wave-uniform scalar loads
        {
            int n = lane;
            int node = tbase + n;
            int dbase = wave * 16;
            float acc[16];
#pragma unroll
            for (int dd = 0; dd < 16; ++dd) acc[dd] = b1[dbase + dd];
            int swz = n & 15;
            const float2* Sn = S + n * 128;
#pragma unroll 4
            for (int m = 0; m < 128; ++m) {
                float2 s = Sn[m ^ swz];
                const float2* Wm = Wsc + m * 64 + dbase;  // uniform -> s_load
#pragma unroll
                for (int dd = 0; dd < 16; ++dd)
                    acc[dd] = fmaf(Wm[dd].x, s.x, fmaf(Wm[dd].y, s.y, acc[dd]));
            }
            if (node < N_NODES) {
                float4* dstp = (float4*)(h1 + node * 64 + dbase);
#pragma unroll
                for (int p = 0; p < 4; ++p)
                    dstp[p] = make_float4(fmaxf(acc[4 * p], 0.f), fmaxf(acc[4 * p + 1], 0.f),
                                          fmaxf(acc[4 * p + 2], 0.f), fmaxf(acc[4 * p + 3], 0.f));
            }
        }
        __syncthreads();
    }
}

// ---------------- SAGE layer 2: same structure, 64-dim in, 16 out ----------------
// LDS float2 tile: node n, m in [0,64) at S2[n*64 + (m ^ (n&15))]
// m<32: (mean2[2m],mean2[2m+1]) ; m>=32: (h1[2m'],h1[2m'+1])

__launch_bounds__(256)
__global__ void k_layer2(const float* __restrict__ h1, const int* __restrict__ ssrc,
                         const int* __restrict__ offs, const int* __restrict__ deg,
                         const float2* __restrict__ Wsc, const float* __restrict__ b2,
                         float* __restrict__ h2) {
    __shared__ float S[64 * 128];  // 32 KB (float view; float2 element = 2 floats)
    int tid = threadIdx.x;
    int wave = __builtin_amdgcn_readfirstlane(tid >> 6);
    int lane = tid & 63;

    int nTiles = (N_NODES + 63) / 64;
    for (int tile = blockIdx.x; tile < nTiles; tile += gridDim.x) {
        int tbase = tile * 64;
        for (int j = wave * 16; j < wave * 16 + 16; ++j) {
            int node = tbase + j;
            if (node < N_NODES) {
                int o  = __builtin_amdgcn_readfirstlane(offs[node]);
                int dg = __builtin_amdgcn_readfirstlane(deg[node]);
                float a0 = 0.f, a1 = 0.f, a2 = 0.f, a3 = 0.f;
                int last = dg - 1;
                for (int u = 0; u < dg; u += 4) {
                    int n0 = ssrc[o + u];
                    int n1 = ssrc[o + min(u + 1, last)];
                    int n2 = ssrc[o + min(u + 2, last)];
                    int n3 = ssrc[o + min(u + 3, last)];
                    float v0 = h1[n0 * 64 + lane];
                    float v1 = h1[n1 * 64 + lane];
                    float v2 = h1[n2 * 64 + lane];
                    float v3 = h1[n3 * 64 + lane];
                    float m1 = (u + 1 < dg) ? 1.f : 0.f;
                    float m2 = (u + 2 < dg) ? 1.f : 0.f;
                    float m3 = (u + 3 < dg) ? 1.f : 0.f;
                    a0 += v0;
                    a1 = fmaf(v1, m1, a1);
                    a2 = fmaf(v2, m2, a2);
                    a3 = fmaf(v3, m3, a3);
                }
                float inv = 1.f / (float)max(dg, 1);
                float mv = ((a0 + a1) + (a2 + a3)) * inv;
                float hv = h1[node * 64 + lane];
                // mean2 k=lane -> float2 elem m=lane>>1 comp lane&1 ; h1 k=lane -> m=32+(lane>>1)
                int pr = (lane >> 1) ^ (j & 15), c = lane & 1;
                S[j * 128 + 2 * pr + c]      = mv;
                S[j * 128 + 64 + 2 * pr + c] = hv;
            }
        }
        __syncthreads();
        {
            int n = lane;
            int node = tbase + n;
            int dbase = wave * 4;
            float acc[4];
#pragma unroll
            for (int dd = 0; dd < 4; ++dd) acc[dd] = b2[dbase + dd];
            int swz = n & 15;
            const float2* Sn = (const float2*)S + n * 64;
#pragma unroll 4
            for (int m = 0; m < 64; ++m) {
                float2 s = Sn[m ^ swz];
                const float2* Wm = Wsc + m * 16 + dbase;  // uniform -> s_load
#pragma unroll
                for (int dd = 0; dd < 4; ++dd)
                    acc[dd] = fmaf(Wm[dd].x, s.x, fmaf(Wm[dd].y, s.y, acc[dd]));
            }
            if (node < N_NODES) {
                *(float4*)(h2 + node * 16 + dbase) =
                    make_float4(acc[0], acc[1], acc[2], acc[3]);
            }
        }
        __syncthreads();
    }
}

// ---------------- graph mean-pool over h2 ----------------

__global__ void k_pool(const float* __restrict__ h2, const int* __restrict__ batch,
                       float* __restrict__ gsum, float* __restrict__ gcnt) {
    __shared__ float bins[N_GRAPHS][17];
    int t = threadIdx.x;
    for (int i = t; i < N_GRAPHS * 17; i += 256) ((float*)bins)[i] = 0.f;
    __syncthreads();
    int dd = t & 15, nl = t >> 4;
    int chunk = (N_NODES + gridDim.x - 1) / gridDim.x;
    int cs = blockIdx.x * chunk;
    int ce = min(N_NODES, cs + chunk);
    for (int n = cs + nl; n < ce; n += 16) {
        float v = h2[n * 16 + dd];
        int g = batch[n];
        atomicAdd(&bins[g][dd], v);
        if (dd == 0) atomicAdd(&bins[g][16], 1.f);
    }
    __syncthreads();
    for (int i = t; i < N_GRAPHS * 17; i += 256) {
        int g = i / 17, c = i - g * 17;
        float v = bins[g][c];
        if (v != 0.f) {
            if (c < 16) atomicAdd(&gsum[g * 16 + c], v);
            else        atomicAdd(&gcnt[g], v);
        }
    }
}

// ---------------- final: BERT head + graph head, concat ----------------

__global__ void k_final(const float* __restrict__ bert, const float* __restrict__ Wad,
                        const float* __restrict__ bad, const float* __restrict__ Wm,
                        const float* __restrict__ bm, const float* __restrict__ gsum,
                        const float* __restrict__ gcnt, float* __restrict__ out) {
    int g = blockIdx.x;
    int t = threadIdx.x;
    if (t < 64) {
        const float4* br = (const float4*)(bert + g * 768);
        const float4* wr = (const float4*)(Wad + t * 768);
        float acc = bad[t];
#pragma unroll 8
        for (int k = 0; k < 192; ++k) {
            float4 bv = br[k], wv = wr[k];
            acc += bv.x * wv.x + bv.y * wv.y + bv.z * wv.z + bv.w * wv.w;
        }
        out[g * 80 + t] = acc;
    } else if (t < 80) {
        int j = t - 64;
        float ic = 1.f / fmaxf(gcnt[g], 1.f);
        float acc = bm[j];
#pragma unroll
        for (int k = 0; k < 16; ++k) acc += Wm[j * 16 + k] * gsum[g * 16 + k] * ic;
        out[g * 80 + t] = acc;
    }
}

extern "C" void kernel_launch(void* const* d_in, const int* in_sizes, int n_in,
                              void* d_out, int out_size, void* d_ws, size_t ws_size,
                              hipStream_t stream) {
    const float* bert   = (const float*)d_in[0];
    const float* node_x = (const float*)d_in[1];
    const int*   edge   = (const int*)d_in[2];
    const int*   batch  = (const int*)d_in[3];
    const float* Wad    = (const float*)d_in[4];
    const float* bad    = (const float*)d_in[5];
    const float* W1l    = (const float*)d_in[6];
    const float* W1r    = (const float*)d_in[7];
    const float* b1     = (const float*)d_in[8];
    const float* W2l    = (const float*)d_in[9];
    const float* W2r    = (const float*)d_in[10];
    const float* b2     = (const float*)d_in[11];
    const float* Wm     = (const float*)d_in[12];
    const float* bm     = (const float*)d_in[13];
    float* out = (float*)d_out;

    const int* src = edge;
    const int* dst = edge + N_EDGES;

    char* ws = (char*)d_ws;
    int*    deg    = (int*)(ws);                //   400,000 B
    int*    offs   = (int*)(ws + 400000);       //   400,000 B
    int*    cursor = (int*)(ws + 800000);       //   400,000 B
    int*    bsums  = (int*)(ws + 1200000);      //       512 B
    int*    boff   = (int*)(ws + 1200512);      //       512 B
    int*    ssrc   = (int*)(ws + 1201024);      // 2,400,000 B
    float*  h1     = (float*)(ws + 3601024);    // 25,600,000 B
    float*  h2     = (float*)(ws + 29201024);   //  6,400,000 B
    float2* Wsc1   = (float2*)(ws + 35601024);  //    65,536 B
    float2* Wsc2   = (float2*)(ws + 35666560);  //     8,192 B
    float*  gsum   = (float*)(ws + 35674752);   //     4,096 B
    float*  gcnt   = (float*)(ws + 35678848);   //       256 B
    // total ~35.7 MB

    hipMemsetAsync(deg, 0, 400000, stream);
    hipMemsetAsync(gsum, 0, 4096 + 256, stream);

    k_count<<<(N_EDGES + 255) / 256, 256, 0, stream>>>(dst, deg);
    k_scan1<<<(N_NODES + 1023) / 1024, 256, 0, stream>>>(deg, offs, bsums);
    k_scan2<<<1, 128, 0, stream>>>(bsums, boff);
    k_scan3<<<(N_NODES + 255) / 256, 256, 0, stream>>>(offs, boff, cursor);
    k_fill<<<(N_EDGES + 255) / 256, 256, 0, stream>>>(src, dst, cursor, ssrc);
    k_prepack1<<<32, 256, 0, stream>>>(W1l, W1r, Wsc1);
    k_prepack2<<<4, 256, 0, stream>>>(W2l, W2r, Wsc2);

    k_layer1<<<512, 256, 0, stream>>>(node_x, ssrc, offs, deg, Wsc1, b1, h1);
    k_layer2<<<1024, 256, 0, stream>>>(h1, ssrc, offs, deg, Wsc2, b2, h2);
    k_pool<<<128, 256, 0, stream>>>(h2, batch, gsum, gcnt);
    k_final<<<N_GRAPHS, 128, 0, stream>>>(bert, Wad, bad, Wm, bm, gsum, gcnt, out);
}

// Round 5
// 357.583 us; speedup vs baseline: 1.2890x; 1.2890x over previous
//
#include <hip/hip_runtime.h>

#define N_NODES 100000
#define N_EDGES 600000
#define N_GRAPHS 64

// ---------------- CSR build ----------------

__global__ void k_count(const int* __restrict__ dst, int* __restrict__ deg) {
    int e = blockIdx.x * 256 + threadIdx.x;
    if (e < N_EDGES) atomicAdd(&deg[dst[e]], 1);
}

__global__ void k_scan1(const int* __restrict__ deg, int* __restrict__ offs,
                        int* __restrict__ bsums) {
    __shared__ int s[256];
    int t = threadIdx.x, b = blockIdx.x;
    int base = b * 1024 + t * 4;
    int v0 = (base + 0 < N_NODES) ? deg[base + 0] : 0;
    int v1 = (base + 1 < N_NODES) ? deg[base + 1] : 0;
    int v2 = (base + 2 < N_NODES) ? deg[base + 2] : 0;
    int v3 = (base + 3 < N_NODES) ? deg[base + 3] : 0;
    int tsum = v0 + v1 + v2 + v3;
    s[t] = tsum;
    __syncthreads();
    for (int o = 1; o < 256; o <<= 1) {
        int x = (t >= o) ? s[t - o] : 0;
        __syncthreads();
        s[t] += x;
        __syncthreads();
    }
    int p = s[t] - tsum;
    if (base + 0 < N_NODES) offs[base + 0] = p;
    p += v0;
    if (base + 1 < N_NODES) offs[base + 1] = p;
    p += v1;
    if (base + 2 < N_NODES) offs[base + 2] = p;
    p += v2;
    if (base + 3 < N_NODES) offs[base + 3] = p;
    if (t == 255) bsums[b] = s[255];
}

__global__ void k_scan2(const int* __restrict__ bsums, int* __restrict__ boff) {
    __shared__ int s[128];
    int t = threadIdx.x;
    int nb = (N_NODES + 1023) / 1024;
    int v = (t < nb) ? bsums[t] : 0;
    s[t] = v;
    __syncthreads();
    for (int o = 1; o < 128; o <<= 1) {
        int x = (t >= o) ? s[t - o] : 0;
        __syncthreads();
        s[t] += x;
        __syncthreads();
    }
    boff[t] = s[t] - v;
}

__global__ void k_scan3(int* __restrict__ offs, const int* __restrict__ boff,
                        int* __restrict__ cursor) {
    int i = blockIdx.x * 256 + threadIdx.x;
    if (i < N_NODES) {
        int v = offs[i] + boff[i >> 10];
        offs[i] = v;
        cursor[i] = v;
    }
}

__global__ void k_fill(const int* __restrict__ src, const int* __restrict__ dst,
                       int* __restrict__ cursor, int* __restrict__ ssrc) {
    int e = blockIdx.x * 256 + threadIdx.x;
    if (e < N_EDGES) {
        int d = dst[e];
        int pos = atomicAdd(&cursor[d], 1);
        ssrc[pos] = src[e];
    }
}

// ---------------- weight prepack (scalar-load layouts) ----------------
// P1l[m*64+d] = (W1l[d][2m], W1l[d][2m+1])   m<64, d<64   @ P[0]
// P1r[m*64+d] = same from W1r                             @ P[4096]
// P2l[m*16+d] = (W2l[d][2m], W2l[d][2m+1])   m<32, d<16   @ P[8192]
// P2r[m*16+d] = same from W2r                             @ P[8704]
__global__ void k_prepack(const float* __restrict__ W1l, const float* __restrict__ W1r,
                          const float* __restrict__ W2l, const float* __restrict__ W2r,
                          float2* __restrict__ P) {
    int i = blockIdx.x * 256 + threadIdx.x;
    if (i < 4096) {
        int m = i >> 6, d = i & 63;
        P[i] = make_float2(W1l[d * 128 + 2 * m], W1l[d * 128 + 2 * m + 1]);
    } else if (i < 8192) {
        int j = i - 4096, m = j >> 6, d = j & 63;
        P[i] = make_float2(W1r[d * 128 + 2 * m], W1r[d * 128 + 2 * m + 1]);
    } else if (i < 8704) {
        int j = i - 8192, m = j >> 4, d = j & 15;
        P[i] = make_float2(W2l[d * 64 + 2 * m], W2l[d * 64 + 2 * m + 1]);
    } else if (i < 9216) {
        int j = i - 8704, m = j >> 4, d = j & 15;
        P[i] = make_float2(W2r[d * 64 + 2 * m], W2r[d * 64 + 2 * m + 1]);
    }
}

// ---------------- xform1: xl = x@W1l.T ; xr (into h1 buf) = x@W1r.T ----------------
// 64-node tile staged in LDS (swizzled float2: S[n*64 + (m ^ (n&31))]), then
// lane=node, wave owns 16 output dims, weights via wave-uniform scalar loads.

__launch_bounds__(256)
__global__ void k_xform1(const float* __restrict__ x,
                         const float2* __restrict__ Pl, const float2* __restrict__ Pr,
                         float* __restrict__ xl, float* __restrict__ xr) {
    __shared__ float2 S[64 * 64];  // 32 KB
    int tid = threadIdx.x;
    int wave = __builtin_amdgcn_readfirstlane(tid >> 6);
    int lane = tid & 63;
    int tbase = blockIdx.x * 64;
    const float4* x4 = (const float4*)x;

    // stage: coalesced float4 loads, swizzled float2 LDS stores
    for (int idx = tid; idx < 64 * 32; idx += 256) {
        int n = idx >> 5, m4 = idx & 31;
        if (tbase + n < N_NODES) {
            float4 v = x4[(tbase + n) * 32 + m4];
            int swz = n & 31;
            S[n * 64 + ((2 * m4) ^ swz)]     = make_float2(v.x, v.y);
            S[n * 64 + ((2 * m4 + 1) ^ swz)] = make_float2(v.z, v.w);
        }
    }
    __syncthreads();

    int node = tbase + lane;
    int dbase = wave * 16;
    float accl[16], accr[16];
#pragma unroll
    for (int dd = 0; dd < 16; ++dd) { accl[dd] = 0.f; accr[dd] = 0.f; }
    int swz = lane & 31;
    const float2* Sn = S + lane * 64;
#pragma unroll 4
    for (int m = 0; m < 64; ++m) {
        float2 s = Sn[m ^ swz];
        const float2* Wl = Pl + m * 64 + dbase;  // uniform -> s_load
        const float2* Wr = Pr + m * 64 + dbase;
#pragma unroll
        for (int dd = 0; dd < 16; ++dd) {
            accl[dd] = fmaf(Wl[dd].x, s.x, fmaf(Wl[dd].y, s.y, accl[dd]));
            accr[dd] = fmaf(Wr[dd].x, s.x, fmaf(Wr[dd].y, s.y, accr[dd]));
        }
    }
    if (node < N_NODES) {
        float4* pl = (float4*)(xl + node * 64 + dbase);
        float4* pr = (float4*)(xr + node * 64 + dbase);
#pragma unroll
        for (int p = 0; p < 4; ++p) {
            pl[p] = make_float4(accl[4 * p], accl[4 * p + 1], accl[4 * p + 2], accl[4 * p + 3]);
            pr[p] = make_float4(accr[4 * p], accr[4 * p + 1], accr[4 * p + 2], accr[4 * p + 3]);
        }
    }
}

// ---------------- gather1: h1[n] = relu(h1[n](=xr) + b1 + mean(xl[nbrs])) ----------
// wave per node, lane = dim. No LDS, no barriers -> max occupancy.

__launch_bounds__(256)
__global__ void k_gather1(const float* __restrict__ xl, const int* __restrict__ ssrc,
                          const int* __restrict__ offs, const int* __restrict__ deg,
                          const float* __restrict__ b1, float* __restrict__ h1) {
    int tid = blockIdx.x * 256 + threadIdx.x;
    int wid = tid >> 6, lane = tid & 63;
    int nWaves = (gridDim.x * 256) >> 6;
    float bias = b1[lane];

    for (int node = wid; node < N_NODES; node += nWaves) {
        int o  = __builtin_amdgcn_readfirstlane(offs[node]);
        int dg = __builtin_amdgcn_readfirstlane(deg[node]);
        float self = h1[node * 64 + lane];  // xr part, prefetched
        float a0 = 0.f, a1 = 0.f, a2 = 0.f, a3 = 0.f;
        int last = dg - 1;
        for (int u = 0; u < dg; u += 4) {
            int n0 = ssrc[o + u];
            int n1 = ssrc[o + min(u + 1, last)];
            int n2 = ssrc[o + min(u + 2, last)];
            int n3 = ssrc[o + min(u + 3, last)];
            float v0 = xl[n0 * 64 + lane];
            float v1 = xl[n1 * 64 + lane];
            float v2 = xl[n2 * 64 + lane];
            float v3 = xl[n3 * 64 + lane];
            float m1 = (u + 1 < dg) ? 1.f : 0.f;
            float m2 = (u + 2 < dg) ? 1.f : 0.f;
            float m3 = (u + 3 < dg) ? 1.f : 0.f;
            a0 += v0;
            a1 = fmaf(v1, m1, a1);
            a2 = fmaf(v2, m2, a2);
            a3 = fmaf(v3, m3, a3);
        }
        float inv = 1.f / (float)max(dg, 1);
        h1[node * 64 + lane] = fmaxf(self + bias + ((a0 + a1) + (a2 + a3)) * inv, 0.f);
    }
}

// ---------------- xform2: h1l = h1@W2l.T ; h2pre = h1@W2r.T ----------------

__launch_bounds__(256)
__global__ void k_xform2(const float* __restrict__ h1,
                         const float2* __restrict__ Pl, const float2* __restrict__ Pr,
                         float* __restrict__ h1l, float* __restrict__ h2pre) {
    __shared__ float2 S[64 * 32];  // 16 KB
    int tid = threadIdx.x;
    int wave = __builtin_amdgcn_readfirstlane(tid >> 6);
    int lane = tid & 63;
    int tbase = blockIdx.x * 64;
    const float4* h4 = (const float4*)h1;

    for (int idx = tid; idx < 64 * 16; idx += 256) {
        int n = idx >> 4, m4 = idx & 15;
        if (tbase + n < N_NODES) {
            float4 v = h4[(tbase + n) * 16 + m4];
            int swz = n & 31;
            S[n * 32 + ((2 * m4) ^ swz)]     = make_float2(v.x, v.y);
            S[n * 32 + ((2 * m4 + 1) ^ swz)] = make_float2(v.z, v.w);
        }
    }
    __syncthreads();

    int node = tbase + lane;
    int dbase = wave * 4;
    float accl[4] = {0.f, 0.f, 0.f, 0.f};
    float accr[4] = {0.f, 0.f, 0.f, 0.f};
    int swz = lane & 31;
    const float2* Sn = S + lane * 32;
#pragma unroll 4
    for (int m = 0; m < 32; ++m) {
        float2 s = Sn[m ^ swz];
        const float2* Wl = Pl + m * 16 + dbase;  // uniform -> s_load
        const float2* Wr = Pr + m * 16 + dbase;
#pragma unroll
        for (int dd = 0; dd < 4; ++dd) {
            accl[dd] = fmaf(Wl[dd].x, s.x, fmaf(Wl[dd].y, s.y, accl[dd]));
            accr[dd] = fmaf(Wr[dd].x, s.x, fmaf(Wr[dd].y, s.y, accr[dd]));
        }
    }
    if (node < N_NODES) {
        *(float4*)(h1l + node * 16 + dbase)   = make_float4(accl[0], accl[1], accl[2], accl[3]);
        *(float4*)(h2pre + node * 16 + dbase) = make_float4(accr[0], accr[1], accr[2], accr[3]);
    }
}

// ---------------- gather2 + graph pooling ----------------
// h2[n][d] = h2pre[n][d] + b2[d] + mean(h1l[nbrs])[d]; pooled into LDS bins.
// wave = 4 nodes x 16 dims; contiguous chunk per block (sorted batch -> few bins).

__launch_bounds__(256)
__global__ void k_g2pool(const float* __restrict__ h1l, const float* __restrict__ h2pre,
                         const int* __restrict__ ssrc, const int* __restrict__ offs,
                         const int* __restrict__ deg, const int* __restrict__ batch,
                         const float* __restrict__ b2,
                         float* __restrict__ gsum, float* __restrict__ gcnt) {
    __shared__ float bins[N_GRAPHS][17];
    int tid = threadIdx.x;
    for (int i = tid; i < N_GRAPHS * 17; i += 256) ((float*)bins)[i] = 0.f;
    __syncthreads();

    int wave = tid >> 6, lane = tid & 63;
    int sub = lane >> 4, d = lane & 15;
    float bias = b2[d];

    int chunk = (N_NODES + gridDim.x - 1) / gridDim.x;
    int cs = blockIdx.x * chunk;
    int ce = min(N_NODES, cs + chunk);

    for (int base = cs + wave * 4; base < ce; base += 16) {
        int node = base + sub;
        bool valid = node < ce;
        int nn = valid ? node : cs;
        int o = offs[nn], dg = deg[nn];
        float a0 = 0.f, a1 = 0.f, a2 = 0.f, a3 = 0.f;
        int last = dg - 1;
        for (int u = 0; u < dg; u += 4) {
            int n0 = ssrc[o + u];
            int n1 = ssrc[o + min(u + 1, last)];
            int n2 = ssrc[o + min(u + 2, last)];
            int n3 = ssrc[o + min(u + 3, last)];
            float v0 = h1l[n0 * 16 + d];
            float v1 = h1l[n1 * 16 + d];
            float v2 = h1l[n2 * 16 + d];
            float v3 = h1l[n3 * 16 + d];
            float m1 = (u + 1 < dg) ? 1.f : 0.f;
            float m2 = (u + 2 < dg) ? 1.f : 0.f;
            float m3 = (u + 3 < dg) ? 1.f : 0.f;
            a0 += v0;
            a1 = fmaf(v1, m1, a1);
            a2 = fmaf(v2, m2, a2);
            a3 = fmaf(v3, m3, a3);
        }
        float inv = 1.f / (float)max(dg, 1);
        float val = h2pre[nn * 16 + d] + bias + ((a0 + a1) + (a2 + a3)) * inv;
        if (valid) {
            int g = batch[nn];
            atomicAdd(&bins[g][d], val);
            if (d == 0) atomicAdd(&bins[g][16], 1.f);
        }
    }
    __syncthreads();
    for (int i = tid; i < N_GRAPHS * 17; i += 256) {
        int g = i / 17, c = i - g * 17;
        float v = bins[g][c];
        if (v != 0.f) {
            if (c < 16) atomicAdd(&gsum[g * 16 + c], v);
            else        atomicAdd(&gcnt[g], v);
        }
    }
}

// ---------------- final: BERT head + graph head, concat ----------------

__global__ void k_final(const float* __restrict__ bert, const float* __restrict__ Wad,
                        const float* __restrict__ bad, const float* __restrict__ Wm,
                        const float* __restrict__ bm, const float* __restrict__ gsum,
                        const float* __restrict__ gcnt, float* __restrict__ out) {
    int g = blockIdx.x;
    int t = threadIdx.x;
    if (t < 64) {
        const float4* br = (const float4*)(bert + g * 768);
        const float4* wr = (const float4*)(Wad + t * 768);
        float acc = bad[t];
#pragma unroll 8
        for (int k = 0; k < 192; ++k) {
            float4 bv = br[k], wv = wr[k];
            acc += bv.x * wv.x + bv.y * wv.y + bv.z * wv.z + bv.w * wv.w;
        }
        out[g * 80 + t] = acc;
    } else if (t < 80) {
        int j = t - 64;
        float ic = 1.f / fmaxf(gcnt[g], 1.f);
        float acc = bm[j];
#pragma unroll
        for (int k = 0; k < 16; ++k) acc += Wm[j * 16 + k] * gsum[g * 16 + k] * ic;
        out[g * 80 + t] = acc;
    }
}

extern "C" void kernel_launch(void* const* d_in, const int* in_sizes, int n_in,
                              void* d_out, int out_size, void* d_ws, size_t ws_size,
                              hipStream_t stream) {
    const float* bert   = (const float*)d_in[0];
    const float* node_x = (const float*)d_in[1];
    const int*   edge   = (const int*)d_in[2];
    const int*   batch  = (const int*)d_in[3];
    const float* Wad    = (const float*)d_in[4];
    const float* bad    = (const float*)d_in[5];
    const float* W1l    = (const float*)d_in[6];
    const float* W1r    = (const float*)d_in[7];
    const float* b1     = (const float*)d_in[8];
    const float* W2l    = (const float*)d_in[9];
    const float* W2r    = (const float*)d_in[10];
    const float* b2     = (const float*)d_in[11];
    const float* Wm     = (const float*)d_in[12];
    const float* bm     = (const float*)d_in[13];
    float* out = (float*)d_out;

    const int* src = edge;
    const int* dst = edge + N_EDGES;

    char* ws = (char*)d_ws;
    int*    deg    = (int*)(ws);                //   400,000 B
    int*    offs   = (int*)(ws + 400000);       //   400,000 B
    int*    cursor = (int*)(ws + 800000);       //   400,000 B
    int*    bsums  = (int*)(ws + 1200000);      //       512 B
    int*    boff   = (int*)(ws + 1200512);      //       512 B
    int*    ssrc   = (int*)(ws + 1201024);      // 2,400,000 B
    float*  xl     = (float*)(ws + 3601024);    // 25,600,000 B  (layer1 projected-l)
    float*  h1     = (float*)(ws + 29201024);   // 25,600,000 B  (xr, then h1 in-place)
    float2* P      = (float2*)(ws + 54801024);  //    73,728 B  (weight packs)
    float*  gsum   = (float*)(ws + 54874752);   //     4,096 B
    float*  gcnt   = (float*)(ws + 54878848);   //       256 B
    // layer-2 buffers alias dead xl region:
    float*  h1l    = (float*)(ws + 3601024);    //  6,400,000 B
    float*  h2pre  = (float*)(ws + 10001024);   //  6,400,000 B
    // peak ~54.9 MB

    float2* P1l = P;
    float2* P1r = P + 4096;
    float2* P2l = P + 8192;
    float2* P2r = P + 8704;

    hipMemsetAsync(deg, 0, 400000, stream);
    hipMemsetAsync(gsum, 0, 4096 + 256, stream);

    k_count<<<(N_EDGES + 255) / 256, 256, 0, stream>>>(dst, deg);
    k_scan1<<<(N_NODES + 1023) / 1024, 256, 0, stream>>>(deg, offs, bsums);
    k_scan2<<<1, 128, 0, stream>>>(bsums, boff);
    k_scan3<<<(N_NODES + 255) / 256, 256, 0, stream>>>(offs, boff, cursor);
    k_fill<<<(N_EDGES + 255) / 256, 256, 0, stream>>>(src, dst, cursor, ssrc);
    k_prepack<<<36, 256, 0, stream>>>(W1l, W1r, W2l, W2r, P);

    int nTiles = (N_NODES + 63) / 64;  // 1563
    k_xform1<<<nTiles, 256, 0, stream>>>(node_x, P1l, P1r, xl, h1);
    k_gather1<<<2048, 256, 0, stream>>>(xl, ssrc, offs, deg, b1, h1);
    k_xform2<<<nTiles, 256, 0, stream>>>(h1, P2l, P2r, h1l, h2pre);
    k_g2pool<<<512, 256, 0, stream>>>(h1l, h2pre, ssrc, offs, deg, batch, b2, gsum, gcnt);
    k_final<<<N_GRAPHS, 128, 0, stream>>>(bert, Wad, bad, Wm, bm, gsum, gcnt, out);
}

// Round 6
// 325.237 us; speedup vs baseline: 1.4172x; 1.0995x over previous
//
#include <hip/hip_runtime.h>

#define N_NODES 100000
#define N_EDGES 600000
#define N_GRAPHS 64

// ---------------- CSR build ----------------

__global__ void k_count(const int* __restrict__ dst, int* __restrict__ deg) {
    int e = blockIdx.x * 256 + threadIdx.x;
    if (e < N_EDGES) atomicAdd(&deg[dst[e]], 1);
}

__global__ void k_scan1(const int* __restrict__ deg, int* __restrict__ offs,
                        int* __restrict__ bsums) {
    __shared__ int s[256];
    int t = threadIdx.x, b = blockIdx.x;
    int base = b * 1024 + t * 4;
    int v0 = (base + 0 < N_NODES) ? deg[base + 0] : 0;
    int v1 = (base + 1 < N_NODES) ? deg[base + 1] : 0;
    int v2 = (base + 2 < N_NODES) ? deg[base + 2] : 0;
    int v3 = (base + 3 < N_NODES) ? deg[base + 3] : 0;
    int tsum = v0 + v1 + v2 + v3;
    s[t] = tsum;
    __syncthreads();
    for (int o = 1; o < 256; o <<= 1) {
        int x = (t >= o) ? s[t - o] : 0;
        __syncthreads();
        s[t] += x;
        __syncthreads();
    }
    int p = s[t] - tsum;
    if (base + 0 < N_NODES) offs[base + 0] = p;
    p += v0;
    if (base + 1 < N_NODES) offs[base + 1] = p;
    p += v1;
    if (base + 2 < N_NODES) offs[base + 2] = p;
    p += v2;
    if (base + 3 < N_NODES) offs[base + 3] = p;
    if (t == 255) bsums[b] = s[255];
}

__global__ void k_scan2(const int* __restrict__ bsums, int* __restrict__ boff) {
    __shared__ int s[128];
    int t = threadIdx.x;
    int nb = (N_NODES + 1023) / 1024;
    int v = (t < nb) ? bsums[t] : 0;
    s[t] = v;
    __syncthreads();
    for (int o = 1; o < 128; o <<= 1) {
        int x = (t >= o) ? s[t - o] : 0;
        __syncthreads();
        s[t] += x;
        __syncthreads();
    }
    boff[t] = s[t] - v;
}

__global__ void k_scan3(int* __restrict__ offs, const int* __restrict__ boff,
                        int* __restrict__ cursor) {
    int i = blockIdx.x * 256 + threadIdx.x;
    if (i < N_NODES) {
        int v = offs[i] + boff[i >> 10];
        offs[i] = v;
        cursor[i] = v;
    }
}

__global__ void k_fill(const int* __restrict__ src, const int* __restrict__ dst,
                       int* __restrict__ cursor, int* __restrict__ ssrc) {
    int e = blockIdx.x * 256 + threadIdx.x;
    if (e < N_EDGES) {
        int d = dst[e];
        int pos = atomicAdd(&cursor[d], 1);
        ssrc[pos] = src[e];
    }
}

// ---------------- weight prepack ----------------
// Pg[k*128 + d]: d<64 -> W1l[d][k], d>=64 -> W1r[d-64][k]   (GEMM B-matrix, row k contiguous)
// P2l[m*16+d] = (W2l[d][2m], W2l[d][2m+1])  m<32, d<16
// P2r[m*16+d] = same from W2r
__global__ void k_prepack(const float* __restrict__ W1l, const float* __restrict__ W1r,
                          const float* __restrict__ W2l, const float* __restrict__ W2r,
                          float* __restrict__ Pg, float2* __restrict__ P2) {
    int i = blockIdx.x * 256 + threadIdx.x;
    if (i < 16384) {
        int k = i >> 7, d = i & 127;
        Pg[i] = (d < 64) ? W1l[d * 128 + k] : W1r[(d - 64) * 128 + k];
    } else if (i < 16896) {
        int j = i - 16384, m = j >> 4, d = j & 15;
        P2[j] = make_float2(W2l[d * 64 + 2 * m], W2l[d * 64 + 2 * m + 1]);
    } else if (i < 17408) {
        int j = i - 16896, m = j >> 4, d = j & 15;
        P2[512 + j] = make_float2(W2r[d * 64 + 2 * m], W2r[d * 64 + 2 * m + 1]);
    }
}

// ---------------- xform1: register-blocked fp32 GEMM ----------------
// C[128 nodes x 128 dims] per block; dims 0..63 -> xl, 64..127 -> xr (h1 buf).
// 4 waves in 2x2; lane owns 8x8 micro-tile; A,B staged in LDS (padded stride).

#define KC 32
#define LDP 132  // LDS row stride in floats (528 B, 16B-aligned)

__launch_bounds__(256, 4)
__global__ void k_xform1(const float* __restrict__ x, const float* __restrict__ Pg,
                         float* __restrict__ xl, float* __restrict__ xr) {
    __shared__ float At[KC * LDP];  // At[kk][n]  n<128  (x tile, transposed)
    __shared__ float Bt[KC * LDP];  // Bt[kk][d]  d<128  (weights)
    int tid = threadIdx.x;
    int wave = tid >> 6, lane = tid & 63;
    int wr = wave >> 1, wc = wave & 1;
    int li = lane >> 3, lj = lane & 7;
    int tbase = blockIdx.x * 128;
    const float4* x4 = (const float4*)x;
    const float4* Pg4 = (const float4*)Pg;

    float acc[8][8];
#pragma unroll
    for (int i = 0; i < 8; ++i)
#pragma unroll
        for (int j = 0; j < 8; ++j) acc[i][j] = 0.f;

    for (int k0 = 0; k0 < 128; k0 += KC) {
        if (k0) __syncthreads();
        // stage A: idx = n*8+q -> x[tbase+n][k0+4q..+3], stored transposed
#pragma unroll
        for (int u = 0; u < 4; ++u) {
            int idx = u * 256 + tid;
            int n = idx >> 3, q = idx & 7;
            int node = min(tbase + n, N_NODES - 1);
            float4 v = x4[node * 32 + (k0 >> 2) + q];
            At[(4 * q + 0) * LDP + n] = v.x;
            At[(4 * q + 1) * LDP + n] = v.y;
            At[(4 * q + 2) * LDP + n] = v.z;
            At[(4 * q + 3) * LDP + n] = v.w;
        }
        // stage B: idx = kk*32+q -> Pg[(k0+kk)*128 + 4q..+3]
#pragma unroll
        for (int u = 0; u < 4; ++u) {
            int idx = u * 256 + tid;
            int kk = idx >> 5, q = idx & 31;
            float4 w = Pg4[(k0 + kk) * 32 + q];
            *(float4*)&Bt[kk * LDP + 4 * q] = w;
        }
        __syncthreads();
#pragma unroll 4
        for (int kk = 0; kk < KC; ++kk) {
            float a[8], b[8];
            *(float4*)&a[0] = *(const float4*)&At[kk * LDP + wr * 64 + li * 8];
            *(float4*)&a[4] = *(const float4*)&At[kk * LDP + wr * 64 + li * 8 + 4];
            *(float4*)&b[0] = *(const float4*)&Bt[kk * LDP + wc * 64 + lj * 8];
            *(float4*)&b[4] = *(const float4*)&Bt[kk * LDP + wc * 64 + lj * 8 + 4];
#pragma unroll
            for (int i = 0; i < 8; ++i)
#pragma unroll
                for (int j = 0; j < 8; ++j)
                    acc[i][j] = fmaf(a[i], b[j], acc[i][j]);
        }
    }
    // epilogue: wc==0 -> xl, wc==1 -> xr; dims lj*8..lj*8+7 within the buffer
    float* outb = wc ? xr : xl;
#pragma unroll
    for (int i = 0; i < 8; ++i) {
        int node = tbase + wr * 64 + li * 8 + i;
        if (node < N_NODES) {
            float4* p = (float4*)(outb + node * 64 + lj * 8);
            p[0] = make_float4(acc[i][0], acc[i][1], acc[i][2], acc[i][3]);
            p[1] = make_float4(acc[i][4], acc[i][5], acc[i][6], acc[i][7]);
        }
    }
}

// ---------------- gather1: h1[n] = relu(h1[n](=xr) + b1 + mean(xl[nbrs])) ----------
// wave per node, lane = dim. No LDS, no barriers -> max occupancy.

__launch_bounds__(256)
__global__ void k_gather1(const float* __restrict__ xl, const int* __restrict__ ssrc,
                          const int* __restrict__ offs, const int* __restrict__ deg,
                          const float* __restrict__ b1, float* __restrict__ h1) {
    int tid = blockIdx.x * 256 + threadIdx.x;
    int wid = tid >> 6, lane = tid & 63;
    int nWaves = (gridDim.x * 256) >> 6;
    float bias = b1[lane];

    for (int node = wid; node < N_NODES; node += nWaves) {
        int o  = __builtin_amdgcn_readfirstlane(offs[node]);
        int dg = __builtin_amdgcn_readfirstlane(deg[node]);
        float self = h1[node * 64 + lane];  // xr part, prefetched
        float a0 = 0.f, a1 = 0.f, a2 = 0.f, a3 = 0.f;
        int last = dg - 1;
        for (int u = 0; u < dg; u += 4) {
            int n0 = ssrc[o + u];
            int n1 = ssrc[o + min(u + 1, last)];
            int n2 = ssrc[o + min(u + 2, last)];
            int n3 = ssrc[o + min(u + 3, last)];
            float v0 = xl[n0 * 64 + lane];
            float v1 = xl[n1 * 64 + lane];
            float v2 = xl[n2 * 64 + lane];
            float v3 = xl[n3 * 64 + lane];
            float m1 = (u + 1 < dg) ? 1.f : 0.f;
            float m2 = (u + 2 < dg) ? 1.f : 0.f;
            float m3 = (u + 3 < dg) ? 1.f : 0.f;
            a0 += v0;
            a1 = fmaf(v1, m1, a1);
            a2 = fmaf(v2, m2, a2);
            a3 = fmaf(v3, m3, a3);
        }
        float inv = 1.f / (float)max(dg, 1);
        h1[node * 64 + lane] = fmaxf(self + bias + ((a0 + a1) + (a2 + a3)) * inv, 0.f);
    }
}

// ---------------- xform2: h1l = h1@W2l.T ; h2pre = h1@W2r.T ----------------

__launch_bounds__(256)
__global__ void k_xform2(const float* __restrict__ h1,
                         const float2* __restrict__ Pl, const float2* __restrict__ Pr,
                         float* __restrict__ h1l, float* __restrict__ h2pre) {
    __shared__ float2 S[64 * 32];  // 16 KB
    int tid = threadIdx.x;
    int wave = __builtin_amdgcn_readfirstlane(tid >> 6);
    int lane = tid & 63;
    int tbase = blockIdx.x * 64;
    const float4* h4 = (const float4*)h1;

    for (int idx = tid; idx < 64 * 16; idx += 256) {
        int n = idx >> 4, m4 = idx & 15;
        if (tbase + n < N_NODES) {
            float4 v = h4[(tbase + n) * 16 + m4];
            int swz = n & 31;
            S[n * 32 + ((2 * m4) ^ swz)]     = make_float2(v.x, v.y);
            S[n * 32 + ((2 * m4 + 1) ^ swz)] = make_float2(v.z, v.w);
        }
    }
    __syncthreads();

    int node = tbase + lane;
    int dbase = wave * 4;
    float accl[4] = {0.f, 0.f, 0.f, 0.f};
    float accr[4] = {0.f, 0.f, 0.f, 0.f};
    int swz = lane & 31;
    const float2* Sn = S + lane * 32;
#pragma unroll 4
    for (int m = 0; m < 32; ++m) {
        float2 s = Sn[m ^ swz];
        const float2* Wl = Pl + m * 16 + dbase;  // uniform -> s_load
        const float2* Wr = Pr + m * 16 + dbase;
#pragma unroll
        for (int dd = 0; dd < 4; ++dd) {
            accl[dd] = fmaf(Wl[dd].x, s.x, fmaf(Wl[dd].y, s.y, accl[dd]));
            accr[dd] = fmaf(Wr[dd].x, s.x, fmaf(Wr[dd].y, s.y, accr[dd]));
        }
    }
    if (node < N_NODES) {
        *(float4*)(h1l + node * 16 + dbase)   = make_float4(accl[0], accl[1], accl[2], accl[3]);
        *(float4*)(h2pre + node * 16 + dbase) = make_float4(accr[0], accr[1], accr[2], accr[3]);
    }
}

// ---------------- gather2 + graph pooling ----------------

__launch_bounds__(256)
__global__ void k_g2pool(const float* __restrict__ h1l, const float* __restrict__ h2pre,
                         const int* __restrict__ ssrc, const int* __restrict__ offs,
                         const int* __restrict__ deg, const int* __restrict__ batch,
                         const float* __restrict__ b2,
                         float* __restrict__ gsum, float* __restrict__ gcnt) {
    __shared__ float bins[N_GRAPHS][17];
    int tid = threadIdx.x;
    for (int i = tid; i < N_GRAPHS * 17; i += 256) ((float*)bins)[i] = 0.f;
    __syncthreads();

    int wave = tid >> 6, lane = tid & 63;
    int sub = lane >> 4, d = lane & 15;
    float bias = b2[d];

    int chunk = (N_NODES + gridDim.x - 1) / gridDim.x;
    int cs = blockIdx.x * chunk;
    int ce = min(N_NODES, cs + chunk);

    for (int base = cs + wave * 4; base < ce; base += 16) {
        int node = base + sub;
        bool valid = node < ce;
        int nn = valid ? node : cs;
        int o = offs[nn], dg = deg[nn];
        float a0 = 0.f, a1 = 0.f, a2 = 0.f, a3 = 0.f;
        int last = dg - 1;
        for (int u = 0; u < dg; u += 4) {
            int n0 = ssrc[o + u];
            int n1 = ssrc[o + min(u + 1, last)];
            int n2 = ssrc[o + min(u + 2, last)];
            int n3 = ssrc[o + min(u + 3, last)];
            float v0 = h1l[n0 * 16 + d];
            float v1 = h1l[n1 * 16 + d];
            float v2 = h1l[n2 * 16 + d];
            float v3 = h1l[n3 * 16 + d];
            float m1 = (u + 1 < dg) ? 1.f : 0.f;
            float m2 = (u + 2 < dg) ? 1.f : 0.f;
            float m3 = (u + 3 < dg) ? 1.f : 0.f;
            a0 += v0;
            a1 = fmaf(v1, m1, a1);
            a2 = fmaf(v2, m2, a2);
            a3 = fmaf(v3, m3, a3);
        }
        float inv = 1.f / (float)max(dg, 1);
        float val = h2pre[nn * 16 + d] + bias + ((a0 + a1) + (a2 + a3)) * inv;
        if (valid) {
            int g = batch[nn];
            atomicAdd(&bins[g][d], val);
            if (d == 0) atomicAdd(&bins[g][16], 1.f);
        }
    }
    __syncthreads();
    for (int i = tid; i < N_GRAPHS * 17; i += 256) {
        int g = i / 17, c = i - g * 17;
        float v = bins[g][c];
        if (v != 0.f) {
            if (c < 16) atomicAdd(&gsum[g * 16 + c], v);
            else        atomicAdd(&gcnt[g], v);
        }
    }
}

// ---------------- final: BERT head + graph head, concat ----------------

__global__ void k_final(const float* __restrict__ bert, const float* __restrict__ Wad,
                        const float* __restrict__ bad, const float* __restrict__ Wm,
                        const float* __restrict__ bm, const float* __restrict__ gsum,
                        const float* __restrict__ gcnt, float* __restrict__ out) {
    int g = blockIdx.x;
    int t = threadIdx.x;
    if (t < 64) {
        const float4* br = (const float4*)(bert + g * 768);
        const float4* wr = (const float4*)(Wad + t * 768);
        float acc = bad[t];
#pragma unroll 8
        for (int k = 0; k < 192; ++k) {
            float4 bv = br[k], wv = wr[k];
            acc += bv.x * wv.x + bv.y * wv.y + bv.z * wv.z + bv.w * wv.w;
        }
        out[g * 80 + t] = acc;
    } else if (t < 80) {
        int j = t - 64;
        float ic = 1.f / fmaxf(gcnt[g], 1.f);
        float acc = bm[j];
#pragma unroll
        for (int k = 0; k < 16; ++k) acc += Wm[j * 16 + k] * gsum[g * 16 + k] * ic;
        out[g * 80 + t] = acc;
    }
}

extern "C" void kernel_launch(void* const* d_in, const int* in_sizes, int n_in,
                              void* d_out, int out_size, void* d_ws, size_t ws_size,
                              hipStream_t stream) {
    const float* bert   = (const float*)d_in[0];
    const float* node_x = (const float*)d_in[1];
    const int*   edge   = (const int*)d_in[2];
    const int*   batch  = (const int*)d_in[3];
    const float* Wad    = (const float*)d_in[4];
    const float* bad    = (const float*)d_in[5];
    const float* W1l    = (const float*)d_in[6];
    const float* W1r    = (const float*)d_in[7];
    const float* b1     = (const float*)d_in[8];
    const float* W2l    = (const float*)d_in[9];
    const float* W2r    = (const float*)d_in[10];
    const float* b2     = (const float*)d_in[11];
    const float* Wm     = (const float*)d_in[12];
    const float* bm     = (const float*)d_in[13];
    float* out = (float*)d_out;

    const int* src = edge;
    const int* dst = edge + N_EDGES;

    char* ws = (char*)d_ws;
    int*    deg    = (int*)(ws);                //   400,000 B
    int*    offs   = (int*)(ws + 400000);       //   400,000 B
    int*    cursor = (int*)(ws + 800000);       //   400,000 B
    int*    bsums  = (int*)(ws + 1200000);      //       512 B
    int*    boff   = (int*)(ws + 1200512);      //       512 B
    int*    ssrc   = (int*)(ws + 1201024);      // 2,400,000 B
    float*  xl     = (float*)(ws + 3601024);    // 25,600,000 B  (layer1 projected-l)
    float*  h1     = (float*)(ws + 29201024);   // 25,600,000 B  (xr, then h1 in-place)
    float*  Pg     = (float*)(ws + 54801024);   //    65,536 B  (xform1 weights, [k][dcomb])
    float2* P2     = (float2*)(ws + 54866560);  //     8,192 B  (xform2 weights)
    float*  gsum   = (float*)(ws + 54874752);   //     4,096 B
    float*  gcnt   = (float*)(ws + 54878848);   //       256 B
    // layer-2 buffers alias dead xl region:
    float*  h1l    = (float*)(ws + 3601024);    //  6,400,000 B
    float*  h2pre  = (float*)(ws + 10001024);   //  6,400,000 B
    // peak ~54.9 MB

    float2* P2l = P2;
    float2* P2r = P2 + 512;

    hipMemsetAsync(deg, 0, 400000, stream);
    hipMemsetAsync(gsum, 0, 4096 + 256, stream);

    k_count<<<(N_EDGES + 255) / 256, 256, 0, stream>>>(dst, deg);
    k_scan1<<<(N_NODES + 1023) / 1024, 256, 0, stream>>>(deg, offs, bsums);
    k_scan2<<<1, 128, 0, stream>>>(bsums, boff);
    k_scan3<<<(N_NODES + 255) / 256, 256, 0, stream>>>(offs, boff, cursor);
    k_fill<<<(N_EDGES + 255) / 256, 256, 0, stream>>>(src, dst, cursor, ssrc);
    k_prepack<<<68, 256, 0, stream>>>(W1l, W1r, W2l, W2r, Pg, P2);

    int nT128 = (N_NODES + 127) / 128;  // 782
    int nT64  = (N_NODES + 63) / 64;    // 1563
    k_xform1<<<nT128, 256, 0, stream>>>(node_x, Pg, xl, h1);
    k_gather1<<<2048, 256, 0, stream>>>(xl, ssrc, offs, deg, b1, h1);
    k_xform2<<<nT64, 256, 0, stream>>>(h1, P2l, P2r, h1l, h2pre);
    k_g2pool<<<512, 256, 0, stream>>>(h1l, h2pre, ssrc, offs, deg, batch, b2, gsum, gcnt);
    k_final<<<N_GRAPHS, 128, 0, stream>>>(bert, Wad, bad, Wm, bm, gsum, gcnt, out);
}